// Round 8
// baseline (850.114 us; speedup 1.0000x reference)
//
#include <hip/hip_runtime.h>
#include <hip/hip_bf16.h>
#include <math.h>

#define NN    8192
#define EE    262144
#define FIN   512
#define HH1   256
#define HH2   64
#define HEADS 3

// ---------------------------------------------------------------- CSR build
__global__ void deg_count_kernel(const int* __restrict__ dst, int* __restrict__ deg) {
    int e = blockIdx.x * blockDim.x + threadIdx.x;
    if (e < EE) atomicAdd(&deg[dst[e]], 1);
}

// single block of 256 threads: exclusive scan over 8192 degrees + inv_sqrt
// NOTE: rowptr buffer MUST hold 8193 ints (writes rowptr[NN]) — round-7 bug
// was rowptr[8192] aliasing cursor[0], emptying node 8191's neighbor list.
__global__ void scan_kernel(const int* __restrict__ deg, int* __restrict__ rowptr,
                            int* __restrict__ cursor, float* __restrict__ invs) {
    __shared__ int part[256];
    int t = threadIdx.x;
    int base = t * 32;
    int s = 0;
    for (int i = 0; i < 32; ++i) s += deg[base + i];
    part[t] = s;
    __syncthreads();
    if (t == 0) {
        int run = 0;
        for (int i = 0; i < 256; ++i) { int v = part[i]; part[i] = run; run += v; }
        rowptr[NN] = run;
    }
    __syncthreads();
    int run = part[t];
    for (int i = 0; i < 32; ++i) {
        int idx = base + i;
        rowptr[idx] = run;
        cursor[idx] = run;
        invs[idx] = rsqrtf(1.0f + (float)deg[idx]);
        run += deg[idx];
    }
}

__global__ void scatter_kernel(const int* __restrict__ src, const int* __restrict__ dst,
                               int* __restrict__ cursor, int* __restrict__ colsrc) {
    int e = blockIdx.x * blockDim.x + threadIdx.x;
    if (e < EE) {
        int d = dst[e];
        int pos = atomicAdd(&cursor[d], 1);
        colsrc[pos] = src[e];
    }
}

// ------------------------------------------------- normalized aggregation
// Y[n][:] = sum_{s in nbr(n)} X[s][:] * invs[s]*invs[n]  +  X[n][:] * invs[n]^2
__global__ __launch_bounds__(256) void aggregate_kernel(
    const float* __restrict__ X, float* __restrict__ Y,
    const int* __restrict__ rowptr, const int* __restrict__ colsrc,
    const float* __restrict__ invs, int F)
{
    int n = blockIdx.x;
    int tid = threadIdx.x;
    float isn = invs[n];
    int beg = rowptr[n], end = rowptr[n + 1];
    int f0 = tid, f1 = tid + 256;
    float acc0 = 0.f, acc1 = 0.f;
    bool has1 = (f1 < F);
    for (int j = beg; j < end; ++j) {
        int s = colsrc[j];
        float w = invs[s] * isn;
        acc0 += X[(long long)s * F + f0] * w;
        if (has1) acc1 += X[(long long)s * F + f1] * w;
    }
    float sw = isn * isn;
    acc0 += X[(long long)n * F + f0] * sw;
    Y[(long long)n * F + f0] = acc0;
    if (has1) {
        acc1 += X[(long long)n * F + f1] * sw;
        Y[(long long)n * F + f1] = acc1;
    }
}

// ------------------------------------------------------------- f32 GEMM
template<int RELU, int BK>
__global__ __launch_bounds__(256) void gemm_tiled(
    const float* __restrict__ A, long long sAz,
    const float* __restrict__ B, long long sBz,
    const float* __restrict__ bias, long long sBiasz,
    float* __restrict__ C, long long sCz,
    int M, int K, int Nout, int ldc)
{
    A += (long long)blockIdx.z * sAz;
    B += (long long)blockIdx.z * sBz;
    C += (long long)blockIdx.z * sCz;
    if (bias) bias += (long long)blockIdx.z * sBiasz;

    __shared__ float As[BK][64 + 1];
    __shared__ float Bs[BK][64];

    int tid = threadIdx.x;
    int tx = tid & 15, ty = tid >> 4;
    int bm = blockIdx.x * 64, bn = blockIdx.y * 64;

    float acc[4][4] = {};
    for (int k0 = 0; k0 < K; k0 += BK) {
        for (int t = tid; t < 64 * BK; t += 256) {
            int m = t / BK, k = t % BK;
            As[k][m] = A[(long long)(bm + m) * K + k0 + k];
        }
        for (int t = tid; t < BK * 64; t += 256) {
            int k = t / 64, n = t % 64;
            Bs[k][n] = B[(long long)(k0 + k) * Nout + bn + n];
        }
        __syncthreads();
        #pragma unroll
        for (int k = 0; k < BK; ++k) {
            float a[4], b[4];
            #pragma unroll
            for (int i = 0; i < 4; ++i) a[i] = As[k][ty * 4 + i];
            #pragma unroll
            for (int j = 0; j < 4; ++j) b[j] = Bs[k][tx * 4 + j];
            #pragma unroll
            for (int i = 0; i < 4; ++i)
                #pragma unroll
                for (int j = 0; j < 4; ++j)
                    acc[i][j] += a[i] * b[j];
        }
        __syncthreads();
    }
    #pragma unroll
    for (int i = 0; i < 4; ++i) {
        int row = bm + ty * 4 + i;
        #pragma unroll
        for (int j = 0; j < 4; ++j) {
            int col = bn + tx * 4 + j;
            float v = acc[i][j];
            if (bias) v += bias[col];
            if (RELU) v = fmaxf(v, 0.f);
            C[(long long)row * ldc + col] = v;
        }
    }
}

// ------------------------------------------------- threefry2x32 -> normal eps
__device__ inline unsigned rotl32(unsigned x, int r) { return (x << r) | (x >> (32 - r)); }
__device__ inline float bits_to_normal(unsigned b) {
    float f = __uint_as_float((b >> 9) | 0x3f800000u) - 1.0f;
    const float minval = -0.99999994f;
    float u = f * 2.0f + minval;
    return 1.41421356f * erfinvf(u);
}

__global__ void eps_kernel(float* __restrict__ eps) {
    const unsigned half = (HEADS * NN * HH2) / 2;  // 786432
    unsigned p = blockIdx.x * blockDim.x + threadIdx.x;
    if (p >= half) return;
    const unsigned ks0 = 0u, ks1 = 42u, ks2 = 0u ^ 42u ^ 0x1BD11BDAu;
    unsigned x0 = p + ks0;
    unsigned x1 = (p + half) + ks1;
#define RND(r) { x0 += x1; x1 = rotl32(x1, r); x1 ^= x0; }
    RND(13) RND(15) RND(26) RND(6)
    x0 += ks1; x1 += ks2 + 1u;
    RND(17) RND(29) RND(16) RND(24)
    x0 += ks2; x1 += ks0 + 2u;
    RND(13) RND(15) RND(26) RND(6)
    x0 += ks0; x1 += ks1 + 3u;
    RND(17) RND(29) RND(16) RND(24)
    x0 += ks1; x1 += ks2 + 4u;
    RND(13) RND(15) RND(26) RND(6)
    x0 += ks2; x1 += ks0 + 5u;
#undef RND
    eps[p] = bits_to_normal(x0);
    eps[p + half] = bits_to_normal(x1);
}

// --------------------------------------------- z = mu + eps*exp(lv); head-max
__global__ void zmax_kernel(const float* __restrict__ agg,
                            const float* __restrict__ bmu, const float* __restrict__ blv,
                            const float* __restrict__ eps,
                            float* __restrict__ zmax,
                            float* __restrict__ omu, float* __restrict__ olv)
{
    int idx = blockIdx.x * blockDim.x + threadIdx.x;
    if (idx >= NN * HH2) return;
    int n = idx >> 6, f = idx & 63;
    const float* row = agg + (long long)n * 384;
    float mm = -INFINITY, lm = -INFINITY, zm = -INFINITY;
    #pragma unroll
    for (int h = 0; h < HEADS; ++h) {
        float mu = row[h * 64 + f] + bmu[h * 64 + f];
        float lv = row[192 + h * 64 + f] + blv[h * 64 + f];
        float ep = eps[h * (NN * HH2) + idx];
        float z = fmaf(ep, expf(lv), mu);
        mm = fmaxf(mm, mu);
        lm = fmaxf(lm, lv);
        zm = fmaxf(zm, z);
    }
    zmax[idx] = zm;
    omu[idx] = mm;
    olv[idx] = lm;
}

// --------------------------------------- adj = sigmoid(zmax @ zmax^T), 8192^2
__global__ __launch_bounds__(256) void adj_kernel(const float* __restrict__ Z,
                                                  float* __restrict__ out)
{
    __shared__ float Zr[64][65];
    __shared__ float Zc[64][65];
    int tid = threadIdx.x;
    int bx = blockIdx.x, by = blockIdx.y;
    for (int t = tid; t < 64 * 64; t += 256) {
        int r = t >> 6, c = t & 63;
        Zr[r][c] = Z[((by << 6) + r) * 64 + c];
        Zc[r][c] = Z[((bx << 6) + r) * 64 + c];
    }
    __syncthreads();
    int tx = tid & 15, ty = tid >> 4;
    float acc[4][4] = {};
    #pragma unroll
    for (int k = 0; k < 64; ++k) {
        float a[4], b[4];
        #pragma unroll
        for (int i = 0; i < 4; ++i) a[i] = Zr[ty * 4 + i][k];
        #pragma unroll
        for (int j = 0; j < 4; ++j) b[j] = Zc[tx * 4 + j][k];
        #pragma unroll
        for (int i = 0; i < 4; ++i)
            #pragma unroll
            for (int j = 0; j < 4; ++j)
                acc[i][j] += a[i] * b[j];
    }
    #pragma unroll
    for (int i = 0; i < 4; ++i) {
        int row = (by << 6) + ty * 4 + i;
        float4 v;
        v.x = 1.f / (1.f + expf(-acc[i][0]));
        v.y = 1.f / (1.f + expf(-acc[i][1]));
        v.z = 1.f / (1.f + expf(-acc[i][2]));
        v.w = 1.f / (1.f + expf(-acc[i][3]));
        *reinterpret_cast<float4*>(&out[(long long)row * NN + (bx << 6) + tx * 4]) = v;
    }
}

// ---------------------------------------------------------------- launcher
extern "C" void kernel_launch(void* const* d_in, const int* in_sizes, int n_in,
                              void* d_out, int out_size, void* d_ws, size_t ws_size,
                              hipStream_t stream) {
    const float* x    = (const float*)d_in[0];
    const int*   ei   = (const int*)d_in[1];
    const float* W0   = (const float*)d_in[2];
    const float* b0   = (const float*)d_in[3];
    const float* W_mu = (const float*)d_in[4];
    const float* b_mu = (const float*)d_in[5];
    const float* W_lv = (const float*)d_in[6];
    const float* b_lv = (const float*)d_in[7];
    float* out = (float*)d_out;

    const int* srcp = ei;
    const int* dstp = ei + EE;

    // --- small scratch in d_ws (~9.3 MB) ---
    char* w = (char*)d_ws;
    int*   deg    = (int*)w;    w += 32768;                      // 8192 ints
    int*   rowptr = (int*)w;    w += 36864;                      // 9216 ints: rowptr[8192] is USED
    int*   cursor = (int*)w;    w += 32768;
    float* invs   = (float*)w;  w += 32768;
    int*   colsrc = (int*)w;    w += (size_t)EE * 4;             // 1 MB
    float* zmx    = (float*)w;  w += (size_t)NN * HH2 * 4;       // 2 MB (survives until adj)
    float* eps    = (float*)w;  w += (size_t)HEADS * NN * HH2 * 4; // 6 MB

    // --- large scratch inside d_out's adjacency region (dead before adj) ---
    float* px  = out;                 // 16 MB  A@x
    float* h   = out + 4194304;       // 24 MB  layer-1 act
    float* pre = out + 10485760;      // 12 MB  mu||lv pre-prop
    float* agg = out + 13631488;      // 12 MB  propagated mu||lv

    // reference return order: (adj, mu_max, logvar_max)
    float* out_mu = out + (long long)NN * NN;
    float* out_lv = out_mu + (long long)NN * HH2;

    // 1) degrees + CSR
    hipMemsetAsync(deg, 0, 32768, stream);
    deg_count_kernel<<<(EE + 255) / 256, 256, 0, stream>>>(dstp, deg);
    scan_kernel<<<1, 256, 0, stream>>>(deg, rowptr, cursor, invs);
    scatter_kernel<<<(EE + 255) / 256, 256, 0, stream>>>(srcp, dstp, cursor, colsrc);

    // 2) propagate x (A @ x), 512 features
    aggregate_kernel<<<NN, 256, 0, stream>>>(x, px, rowptr, colsrc, invs, FIN);

    // 3) layer-1 GEMM per head: h = relu(px @ W0 + b0)   [3][N][256]
    dim3 g1(NN / 64, HH1 / 64, HEADS);
    gemm_tiled<1, 16><<<g1, 256, 0, stream>>>(px, 0, W0, (long long)FIN * HH1,
                                              b0, HH1, h, (long long)NN * HH1,
                                              NN, FIN, HH1, HH1);

    // 4) layer-2 GEMMs: pre[n][h*64+o] (mu), pre[n][192+h*64+o] (lv)
    dim3 g2(NN / 64, 1, HEADS);
    gemm_tiled<0, 16><<<g2, 256, 0, stream>>>(h, (long long)NN * HH1, W_mu, (long long)HH1 * HH2,
                                              nullptr, 0, pre, 64, NN, HH1, HH2, 384);
    gemm_tiled<0, 16><<<g2, 256, 0, stream>>>(h, (long long)NN * HH1, W_lv, (long long)HH1 * HH2,
                                              nullptr, 0, pre + 192, 64, NN, HH1, HH2, 384);

    // 5) propagate mu||lv together (384 features)
    aggregate_kernel<<<NN, 256, 0, stream>>>(pre, agg, rowptr, colsrc, invs, 384);

    // 6) eps (JAX threefry key 42), z, head-max
    eps_kernel<<<(786432 + 255) / 256, 256, 0, stream>>>(eps);
    zmax_kernel<<<(NN * HH2 + 255) / 256, 256, 0, stream>>>(agg, b_mu, b_lv, eps,
                                                            zmx, out_mu, out_lv);

    // 7) adj = sigmoid(zmax @ zmax^T)  (overwrites scratch region last)
    dim3 ga(NN / 64, NN / 64);
    adj_kernel<<<ga, 256, 0, stream>>>(zmx, out);
}

// Round 11
// 665.819 us; speedup vs baseline: 1.2768x; 1.2768x over previous
//
#include <hip/hip_runtime.h>
#include <hip/hip_bf16.h>
#include <math.h>

#define NN    8192
#define EE    262144
#define FIN   512
#define HH1   256
#define HH2   64
#define HEADS 3

typedef short bf16x8 __attribute__((ext_vector_type(8)));
typedef float f32x4  __attribute__((ext_vector_type(4)));

// ---------------------------------------------------------------- CSR build
__global__ void deg_count_kernel(const int* __restrict__ dst, int* __restrict__ deg) {
    int e = blockIdx.x * blockDim.x + threadIdx.x;
    if (e < EE) atomicAdd(&deg[dst[e]], 1);
}

// rowptr buffer MUST hold 8193 ints (writes rowptr[NN]) — round-7 lesson.
__global__ void scan_kernel(const int* __restrict__ deg, int* __restrict__ rowptr,
                            int* __restrict__ cursor, float* __restrict__ invs) {
    __shared__ int part[256];
    int t = threadIdx.x;
    int base = t * 32;
    int s = 0;
    for (int i = 0; i < 32; ++i) s += deg[base + i];
    part[t] = s;
    __syncthreads();
    if (t == 0) {
        int run = 0;
        for (int i = 0; i < 256; ++i) { int v = part[i]; part[i] = run; run += v; }
        rowptr[NN] = run;
    }
    __syncthreads();
    int run = part[t];
    for (int i = 0; i < 32; ++i) {
        int idx = base + i;
        rowptr[idx] = run;
        cursor[idx] = run;
        invs[idx] = rsqrtf(1.0f + (float)deg[idx]);
        run += deg[idx];
    }
}

__global__ void scatter_kernel(const int* __restrict__ src, const int* __restrict__ dst,
                               int* __restrict__ cursor, int* __restrict__ colsrc) {
    int e = blockIdx.x * blockDim.x + threadIdx.x;
    if (e < EE) {
        int d = dst[e];
        int pos = atomicAdd(&cursor[d], 1);
        colsrc[pos] = src[e];
    }
}

// ------------------------------------------------- normalized aggregation (float4)
__global__ __launch_bounds__(128) void aggregate4_kernel(
    const float4* __restrict__ X, float4* __restrict__ Y,
    const int* __restrict__ rowptr, const int* __restrict__ colsrc,
    const float* __restrict__ invs, int F4)
{
    int n = blockIdx.x;
    int t = threadIdx.x;
    if (t >= F4) return;
    float isn = invs[n];
    int beg = rowptr[n], end = rowptr[n + 1];
    float4 a; a.x = 0.f; a.y = 0.f; a.z = 0.f; a.w = 0.f;
    for (int j = beg; j < end; ++j) {
        int s = colsrc[j];
        float w2 = invs[s] * isn;
        float4 v = X[(long long)s * F4 + t];
        a.x += v.x * w2; a.y += v.y * w2; a.z += v.z * w2; a.w += v.w * w2;
    }
    float sw = isn * isn;
    float4 v = X[(long long)n * F4 + t];
    a.x += v.x * sw; a.y += v.y * sw; a.z += v.z * sw; a.w += v.w * sw;
    Y[(long long)n * F4 + t] = a;
}

// ------------------------------------------------- bf16 hi/lo split packing
__device__ inline unsigned bf16_rne(float v) {
    unsigned u = __float_as_uint(v);
    return (u + 0x7FFFu + ((u >> 16) & 1u)) >> 16;
}

// src: 2*npairs f32 -> dhi/dlo u32 planes (2 bf16 per u32, elem k at bit 16*(k&1))
__global__ void pack_split_kernel(const float* __restrict__ src,
                                  unsigned* __restrict__ dhi, unsigned* __restrict__ dlo,
                                  int npairs) {
    int i = blockIdx.x * blockDim.x + threadIdx.x;
    if (i >= npairs) return;
    float v0 = src[2 * i], v1 = src[2 * i + 1];
    unsigned h0 = bf16_rne(v0), h1 = bf16_rne(v1);
    float l0f = v0 - __uint_as_float(h0 << 16);
    float l1f = v1 - __uint_as_float(h1 << 16);
    unsigned l0 = bf16_rne(l0f), l1 = bf16_rne(l1f);
    dhi[i] = (h1 << 16) | h0;
    dlo[i] = (l1 << 16) | l0;
}

// W0 [3][512][256] f32 -> planes [3][256][256] u32 (n-major rows of k32)
__global__ void w0_transpack_kernel(const float* __restrict__ W0,
                                    unsigned* __restrict__ dhi, unsigned* __restrict__ dlo) {
    int idx = blockIdx.x * blockDim.x + threadIdx.x;
    if (idx >= HEADS * 256 * 256) return;
    int n = idx & 255, k32 = (idx >> 8) & 255, hh = idx >> 16;
    float v0 = W0[hh * (FIN * HH1) + (2 * k32) * HH1 + n];
    float v1 = W0[hh * (FIN * HH1) + (2 * k32 + 1) * HH1 + n];
    unsigned h0 = bf16_rne(v0), h1 = bf16_rne(v1);
    float l0f = v0 - __uint_as_float(h0 << 16);
    float l1f = v1 - __uint_as_float(h1 << 16);
    unsigned l0 = bf16_rne(l0f), l1 = bf16_rne(l1f);
    int o = hh * 65536 + n * 256 + k32;
    dhi[o] = (h1 << 16) | h0;
    dlo[o] = (l1 << 16) | l0;
}

// ------------------------------------------------- split-bf16 MFMA GEMM (NT)
// C[m][n] = sum_k A[m][k]*B[n][k]  (both operands row-major over K, pre-packed
// hi/lo planes, 2 bf16/u32).  EPI 0: sigmoid.  EPI 1: +bias, relu.
// Block: 256 thr = 4 waves (2x2 of 64x64), tile 128x128, K-step 64 elems.
// LDS XOR-swizzle (16B-chunk ^ row&7) -> conflict-free ds_read_b128 (guide G4/T2).
template<int EPI>
__global__ __launch_bounds__(256) void mfma_nt_kernel(
    const unsigned* __restrict__ Ahi, const unsigned* __restrict__ Alo, long long sAz,
    const unsigned* __restrict__ Bhi, const unsigned* __restrict__ Blo, long long sBz,
    const float* __restrict__ bias, int sBiasz,
    float* __restrict__ C, long long sCz,
    int K, int ldc)
{
    int z = blockIdx.z;
    Ahi += z * sAz; Alo += z * sAz;
    Bhi += z * sBz; Blo += z * sBz;
    C   += z * sCz;
    if (EPI == 1) bias += (long long)z * sBiasz;

    const int K32 = K >> 1;  // u32 per row
    __shared__ unsigned lds[16384];          // 64 KB: Ahi|Alo|Bhi|Blo planes
    unsigned* sAhi = lds;
    unsigned* sAlo = lds + 4096;
    unsigned* sBhi = lds + 8192;
    unsigned* sBlo = lds + 12288;

    int tid = threadIdx.x;
    int bm = blockIdx.x * 128, bn = blockIdx.y * 128;
    int w = tid >> 6, lane = tid & 63;
    int wr = (w >> 1) * 64, wc = (w & 1) * 64;
    int lm = lane & 15, lg = lane >> 4;

    f32x4 acc[4][4];
    #pragma unroll
    for (int mi = 0; mi < 4; ++mi)
        #pragma unroll
        for (int nj = 0; nj < 4; ++nj)
            acc[mi][nj] = (f32x4){0.f, 0.f, 0.f, 0.f};

    for (int k0 = 0; k0 < K32; k0 += 32) {
        __syncthreads();   // protect LDS reuse from previous iteration
        for (int i = tid; i < 4096; i += 256) {
            int row = i >> 5, col = i & 31;
            int sw = (row << 5) + ((((col >> 2) ^ (row & 7)) << 2) | (col & 3));
            sAhi[sw] = Ahi[(long long)(bm + row) * K32 + k0 + col];
            sAlo[sw] = Alo[(long long)(bm + row) * K32 + k0 + col];
            sBhi[sw] = Bhi[(long long)(bn + row) * K32 + k0 + col];
            sBlo[sw] = Blo[(long long)(bn + row) * K32 + k0 + col];
        }
        __syncthreads();
        #pragma unroll
        for (int ks = 0; ks < 2; ++ks) {
            bf16x8 ahi[4], alo[4], bhi[4], blo[4];
            int c = ks * 4 + lg;   // 16B chunk index 0..7
            #pragma unroll
            for (int mi = 0; mi < 4; ++mi) {
                int row = wr + mi * 16 + lm;
                int addr = (row << 5) + ((c ^ (row & 7)) << 2);
                ahi[mi] = *(const bf16x8*)&sAhi[addr];
                alo[mi] = *(const bf16x8*)&sAlo[addr];
            }
            #pragma unroll
            for (int nj = 0; nj < 4; ++nj) {
                int row = wc + nj * 16 + lm;
                int addr = (row << 5) + ((c ^ (row & 7)) << 2);
                bhi[nj] = *(const bf16x8*)&sBhi[addr];
                blo[nj] = *(const bf16x8*)&sBlo[addr];
            }
            #pragma unroll
            for (int mi = 0; mi < 4; ++mi)
                #pragma unroll
                for (int nj = 0; nj < 4; ++nj) {
                    acc[mi][nj] = __builtin_amdgcn_mfma_f32_16x16x32_bf16(ahi[mi], bhi[nj], acc[mi][nj], 0, 0, 0);
                    acc[mi][nj] = __builtin_amdgcn_mfma_f32_16x16x32_bf16(ahi[mi], blo[nj], acc[mi][nj], 0, 0, 0);
                    acc[mi][nj] = __builtin_amdgcn_mfma_f32_16x16x32_bf16(alo[mi], bhi[nj], acc[mi][nj], 0, 0, 0);
                }
        }
    }

    // epilogue: C/D layout col=lane&15, row=(lane>>4)*4+reg  [guide §3, m89]
    #pragma unroll
    for (int mi = 0; mi < 4; ++mi) {
        #pragma unroll
        for (int nj = 0; nj < 4; ++nj) {
            int gcol = bn + wc + nj * 16 + lm;
            float bv = (EPI == 1) ? bias[gcol] : 0.f;
            #pragma unroll
            for (int r = 0; r < 4; ++r) {
                int grow = bm + wr + mi * 16 + lg * 4 + r;
                float v = acc[mi][nj][r];
                if (EPI == 0) v = 1.f / (1.f + expf(-v));
                else          v = fmaxf(v + bv, 0.f);
                C[(long long)grow * ldc + gcol] = v;
            }
        }
    }
}

// ------------------------------------------------------------- f32 GEMM (layer 2)
template<int RELU, int BK>
__global__ __launch_bounds__(256) void gemm_tiled(
    const float* __restrict__ A, long long sAz,
    const float* __restrict__ B, long long sBz,
    const float* __restrict__ bias, long long sBiasz,
    float* __restrict__ C, long long sCz,
    int M, int K, int Nout, int ldc)
{
    A += (long long)blockIdx.z * sAz;
    B += (long long)blockIdx.z * sBz;
    C += (long long)blockIdx.z * sCz;
    if (bias) bias += (long long)blockIdx.z * sBiasz;

    __shared__ float As[BK][64 + 1];
    __shared__ float Bs[BK][64];

    int tid = threadIdx.x;
    int tx = tid & 15, ty = tid >> 4;
    int bm = blockIdx.x * 64, bn = blockIdx.y * 64;

    float acc[4][4] = {};
    for (int k0 = 0; k0 < K; k0 += BK) {
        for (int t = tid; t < 64 * BK; t += 256) {
            int m = t / BK, k = t % BK;
            As[k][m] = A[(long long)(bm + m) * K + k0 + k];
        }
        for (int t = tid; t < BK * 64; t += 256) {
            int k = t / 64, n = t % 64;
            Bs[k][n] = B[(long long)(k0 + k) * Nout + bn + n];
        }
        __syncthreads();
        #pragma unroll
        for (int k = 0; k < BK; ++k) {
            float a[4], b[4];
            #pragma unroll
            for (int i = 0; i < 4; ++i) a[i] = As[k][ty * 4 + i];
            #pragma unroll
            for (int j = 0; j < 4; ++j) b[j] = Bs[k][tx * 4 + j];
            #pragma unroll
            for (int i = 0; i < 4; ++i)
                #pragma unroll
                for (int j = 0; j < 4; ++j)
                    acc[i][j] += a[i] * b[j];
        }
        __syncthreads();
    }
    #pragma unroll
    for (int i = 0; i < 4; ++i) {
        int row = bm + ty * 4 + i;
        #pragma unroll
        for (int j = 0; j < 4; ++j) {
            int col = bn + tx * 4 + j;
            float v = acc[i][j];
            if (bias) v += bias[col];
            if (RELU) v = fmaxf(v, 0.f);
            C[(long long)row * ldc + col] = v;
        }
    }
}

// ------------------------------------------------- threefry2x32 -> normal eps
__device__ inline unsigned rotl32(unsigned x, int r) { return (x << r) | (x >> (32 - r)); }
__device__ inline float bits_to_normal(unsigned b) {
    float f = __uint_as_float((b >> 9) | 0x3f800000u) - 1.0f;
    const float minval = -0.99999994f;
    float u = f * 2.0f + minval;
    return 1.41421356f * erfinvf(u);
}

__global__ void eps_kernel(float* __restrict__ eps) {
    const unsigned half = (HEADS * NN * HH2) / 2;  // 786432
    unsigned p = blockIdx.x * blockDim.x + threadIdx.x;
    if (p >= half) return;
    const unsigned ks0 = 0u, ks1 = 42u, ks2 = 0u ^ 42u ^ 0x1BD11BDAu;
    unsigned x0 = p + ks0;
    unsigned x1 = (p + half) + ks1;
#define RND(r) { x0 += x1; x1 = rotl32(x1, r); x1 ^= x0; }
    RND(13) RND(15) RND(26) RND(6)
    x0 += ks1; x1 += ks2 + 1u;
    RND(17) RND(29) RND(16) RND(24)
    x0 += ks2; x1 += ks0 + 2u;
    RND(13) RND(15) RND(26) RND(6)
    x0 += ks0; x1 += ks1 + 3u;
    RND(17) RND(29) RND(16) RND(24)
    x0 += ks1; x1 += ks2 + 4u;
    RND(13) RND(15) RND(26) RND(6)
    x0 += ks2; x1 += ks0 + 5u;
#undef RND
    eps[p] = bits_to_normal(x0);
    eps[p + half] = bits_to_normal(x1);
}

// --------------------------------------------- z = mu + eps*exp(lv); head-max
__global__ void zmax_kernel(const float* __restrict__ agg,
                            const float* __restrict__ bmu, const float* __restrict__ blv,
                            const float* __restrict__ eps,
                            float* __restrict__ zmax,
                            float* __restrict__ omu, float* __restrict__ olv)
{
    int idx = blockIdx.x * blockDim.x + threadIdx.x;
    if (idx >= NN * HH2) return;
    int n = idx >> 6, f = idx & 63;
    const float* row = agg + (long long)n * 384;
    float mm = -INFINITY, lm = -INFINITY, zm = -INFINITY;
    #pragma unroll
    for (int h = 0; h < HEADS; ++h) {
        float mu = row[h * 64 + f] + bmu[h * 64 + f];
        float lv = row[192 + h * 64 + f] + blv[h * 64 + f];
        float ep = eps[h * (NN * HH2) + idx];
        float z = fmaf(ep, expf(lv), mu);
        mm = fmaxf(mm, mu);
        lm = fmaxf(lm, lv);
        zm = fmaxf(zm, z);
    }
    zmax[idx] = zm;
    omu[idx] = mm;
    olv[idx] = lm;
}

// ---------------------------------------------------------------- launcher
extern "C" void kernel_launch(void* const* d_in, const int* in_sizes, int n_in,
                              void* d_out, int out_size, void* d_ws, size_t ws_size,
                              hipStream_t stream) {
    const float* x    = (const float*)d_in[0];
    const int*   ei   = (const int*)d_in[1];
    const float* W0   = (const float*)d_in[2];
    const float* b0   = (const float*)d_in[3];
    const float* W_mu = (const float*)d_in[4];
    const float* b_mu = (const float*)d_in[5];
    const float* W_lv = (const float*)d_in[6];
    const float* b_lv = (const float*)d_in[7];
    float* out = (float*)d_out;

    const int* srcp = ei;
    const int* dstp = ei + EE;

    // --- scratch in d_ws (~11.3 MB) ---
    char* w = (char*)d_ws;
    int*      deg    = (int*)w;      w += 32768;
    int*      rowptr = (int*)w;      w += 36864;   // 9216 ints: rowptr[8192] USED
    int*      cursor = (int*)w;      w += 32768;
    float*    invs   = (float*)w;    w += 32768;
    int*      colsrc = (int*)w;      w += (size_t)EE * 4;
    float*    zmx    = (float*)w;    w += (size_t)NN * HH2 * 4;         // 2 MB
    float*    eps    = (float*)w;    w += (size_t)HEADS * NN * HH2 * 4; // 6 MB
    unsigned* zph    = (unsigned*)w; w += (size_t)NN * 32 * 4;          // 1 MB
    unsigned* zpl    = (unsigned*)w; w += (size_t)NN * 32 * 4;          // 1 MB

    // --- large scratch inside d_out's adjacency region (dead before adj) ---
    float*    px   = out;                              // [0, 16MB)
    float*    h    = out + 4194304;                    // [16, 40MB)
    float*    pre  = out + 10485760;                   // [40, 52MB)
    float*    agg  = out + 13631488;                   // [52, 64MB)
    unsigned* pxph = (unsigned*)(out + 16777216);      // [64, 72MB)  px hi plane
    unsigned* pxpl = (unsigned*)(out + 18874368);      // [72, 80MB)  px lo plane
    unsigned* w0h  = (unsigned*)(out + 20971520);      // [80, 80.75MB)
    unsigned* w0l  = (unsigned*)(out + 21168128);      // [80.75, 81.5MB)

    float* out_mu = out + (long long)NN * NN;
    float* out_lv = out_mu + (long long)NN * HH2;

    // 1) degrees + CSR
    hipMemsetAsync(deg, 0, 32768, stream);
    deg_count_kernel<<<(EE + 255) / 256, 256, 0, stream>>>(dstp, deg);
    scan_kernel<<<1, 256, 0, stream>>>(deg, rowptr, cursor, invs);
    scatter_kernel<<<(EE + 255) / 256, 256, 0, stream>>>(srcp, dstp, cursor, colsrc);

    // 2) propagate x (A @ x), 512 features (float4)
    aggregate4_kernel<<<NN, 128, 0, stream>>>((const float4*)x, (float4*)px,
                                              rowptr, colsrc, invs, FIN / 4);

    // 3) pack px + W0 into bf16 hi/lo planes; layer-1 via split-bf16 MFMA
    pack_split_kernel<<<(NN * FIN / 2 + 255) / 256, 256, 0, stream>>>(px, pxph, pxpl, NN * FIN / 2);
    w0_transpack_kernel<<<(HEADS * 256 * 256 + 255) / 256, 256, 0, stream>>>(W0, w0h, w0l);
    {
        dim3 g1(NN / 128, HH1 / 128, HEADS);
        mfma_nt_kernel<1><<<g1, 256, 0, stream>>>(pxph, pxpl, 0LL,
                                                  w0h, w0l, 65536LL,
                                                  b0, HH1,
                                                  h, (long long)NN * HH1,
                                                  FIN, HH1);
    }

    // 4) layer-2 GEMMs (f32): pre[n][h*64+o] (mu), pre[n][192+h*64+o] (lv)
    dim3 g2(NN / 64, 1, HEADS);
    gemm_tiled<0, 16><<<g2, 256, 0, stream>>>(h, (long long)NN * HH1, W_mu, (long long)HH1 * HH2,
                                              nullptr, 0, pre, 64, NN, HH1, HH2, 384);
    gemm_tiled<0, 16><<<g2, 256, 0, stream>>>(h, (long long)NN * HH1, W_lv, (long long)HH1 * HH2,
                                              nullptr, 0, pre + 192, 64, NN, HH1, HH2, 384);

    // 5) propagate mu||lv (384 features, float4)
    aggregate4_kernel<<<NN, 128, 0, stream>>>((const float4*)pre, (float4*)agg,
                                              rowptr, colsrc, invs, 384 / 4);

    // 6) eps (JAX threefry key 42), z, head-max
    eps_kernel<<<(786432 + 255) / 256, 256, 0, stream>>>(eps);
    zmax_kernel<<<(NN * HH2 + 255) / 256, 256, 0, stream>>>(agg, b_mu, b_lv, eps,
                                                            zmx, out_mu, out_lv);

    // 7) adj = sigmoid(zmax @ zmax^T) via split-bf16 MFMA (overwrites scratch last)
    pack_split_kernel<<<(NN * HH2 / 2 + 255) / 256, 256, 0, stream>>>(zmx, zph, zpl, NN * HH2 / 2);
    {
        dim3 ga(NN / 128, NN / 128, 1);
        mfma_nt_kernel<0><<<ga, 256, 0, stream>>>(zph, zpl, 0LL,
                                                  zph, zpl, 0LL,
                                                  nullptr, 0,
                                                  out, 0LL,
                                                  HH2, NN);
    }
}